// Round 1
// baseline (606.537 us; speedup 1.0000x reference)
//
#include <hip/hip_runtime.h>
#include <hip/hip_cooperative_groups.h>

namespace cg = cooperative_groups;

#define GAMMA 0.01f
#define B 32
#define G 2048
#define C 16
#define S 8
#define L 3
#define M 16

// lse in base-2: exp((v)/g) = exp2(v * K_EXP); g*log(s) = K_LOG * log2(s)
#define K_EXP 144.26950408889634f    // log2(e) / GAMMA
#define K_LOG 0.006931471805599453f  // GAMMA * ln(2)

__device__ __forceinline__ float waveMax(float v) {
#pragma unroll
    for (int off = 32; off > 0; off >>= 1)
        v = fmaxf(v, __shfl_xor(v, off, 64));
    return v;
}

// Block-wide max broadcast (256 threads = 4 waves). Leading sync guards scratch.
__device__ __forceinline__ float blockMaxBcast(float v, float* scratch) {
    float wm = waveMax(v);
    __syncthreads();
    if ((threadIdx.x & 63) == 0) scratch[threadIdx.x >> 6] = wm;
    __syncthreads();
    return fmaxf(fmaxf(scratch[0], scratch[1]), fmaxf(scratch[2], scratch[3]));
}

// Block-wide max -> dst[blockIdx.x] (one partial per block, no atomics).
__device__ __forceinline__ void blockMaxOut(float v, float* scratch, float* dst) {
    float wm = waveMax(v);
    __syncthreads();
    if ((threadIdx.x & 63) == 0) scratch[threadIdx.x >> 6] = wm;
    __syncthreads();
    if (threadIdx.x == 0)
        dst[blockIdx.x] =
            fmaxf(fmaxf(scratch[0], scratch[1]), fmaxf(scratch[2], scratch[3]));
}

// Single persistent cooperative kernel: 256 blocks x 256 threads.
// Block = (b = bid>>3, gt = bid&7): owns 256 g's of row b, all 16 c's.
// Per iteration: phase A (gather+prod+lse_S, fused Ws-matmul -> H, Pm1)
//                -> grid.sync -> phase B (s1-scale, lse_M -> Hy, Pm2)
//                -> grid.sync -> phase C (lse_2 with Rprev from LDS -> Ry, Pm3)
//                -> grid.sync.
extern "C" __global__ __launch_bounds__(256) void kmain(
    const float* __restrict__ x, const float* __restrict__ W,
    const int* __restrict__ I, unsigned int* __restrict__ Ipk,
    float* __restrict__ Wst, float* __restrict__ Pm1,
    float* __restrict__ Pm2, float* __restrict__ Pm3,
    float* __restrict__ H, float* __restrict__ Hy,
    float* __restrict__ Ry, float* __restrict__ out)
{
    __shared__ __align__(16) float Vrow[G];   // 8 KB: s-scaled V row for this b
    __shared__ float scratch[4];

    cg::grid_group grid = cg::this_grid();

    const int t = threadIdx.x;
    const int bid = blockIdx.x;
    const int b = bid >> 3;
    const int gt = bid & 7;
    const int g = (gt << 8) + t;
    const int i = (bid << 8) + t;     // == b*G + g (linear over B*G)

    // ---- init: pack I into pre-shifted u16 byte-offsets; Ws=softmax(W) T'd ----
    {
        const uint4* I4 = (const uint4*)I;
        uint4* P4 = (uint4*)Ipk;
        // N = C*G*S*L = 786432 ints -> 98304 output uint4 (8 u16 each)
        for (int j = i; j < (C * G * S * L) / 8; j += B * G) {
            uint4 a = I4[2 * j], c4 = I4[2 * j + 1];
            uint4 o;
            o.x = (a.x << 2) | (a.y << 18);   // idx*4 fits u16 (<= 8188)
            o.y = (a.z << 2) | (a.w << 18);
            o.z = (c4.x << 2) | (c4.y << 18);
            o.w = (c4.z << 2) | (c4.w << 18);
            P4[j] = o;
        }
        if (bid == 0) {                      // Wst[c*M+m] = softmax(W,axis=1)^T
            int m = t >> 4, c = t & 15;
            float rmax = -INFINITY;
#pragma unroll
            for (int j = 0; j < C; j++) rmax = fmaxf(rmax, W[m * C + j]);
            float rsum = 0.f;
#pragma unroll
            for (int j = 0; j < C; j++) rsum += __expf(W[m * C + j] - rmax);
            Wst[c * M + m] = __expf(W[m * C + c] - rmax) / rsum;
        }
    }
    grid.sync();

    float s = 1.0f;              // scale of previous R (sp), lives across phases
    const float* Vsrc = x;

    for (int it = 0; it < 5; it++) {
        // ---------------- phase A ----------------
        if (it > 0) {            // uniform branch
            float m3 = blockMaxBcast(Pm3[t], scratch);
            s = (m3 > 1.0f) ? 1.0f / m3 : 1.0f;
        }
        {
            const float4* V4 = (const float4*)(Vsrc + (size_t)b * G);
            float4* Vr4 = (float4*)Vrow;
#pragma unroll
            for (int j = 0; j < 2; j++) {
                float4 v = V4[t + j * 256];
                v.x *= s; v.y *= s; v.z *= s; v.w *= s;
                Vr4[t + j * 256] = v;
            }
        }
        __syncthreads();

        float h[M];
#pragma unroll
        for (int m = 0; m < M; m++) h[m] = 0.f;
        float ymax = -INFINITY;
        const char* vb = (const char*)Vrow;

        const uint4* ipb = (const uint4*)Ipk + (size_t)g * 3;  // c-stride G*3
        uint4 w0 = ipb[0], w1 = ipb[1], w2 = ipb[2];
#pragma unroll
        for (int c = 0; c < C; c++) {
            uint4 n0, n1, n2;
            if (c + 1 < C) {               // prefetch next c's offsets (L2)
                const uint4* ipn = ipb + (size_t)(c + 1) * (G * 3);
                n0 = ipn[0]; n1 = ipn[1]; n2 = ipn[2];
            }
            unsigned int wq[12] = {w0.x, w0.y, w0.z, w0.w, w1.x, w1.y,
                                   w1.z, w1.w, w2.x, w2.y, w2.z, w2.w};
            float vv[24];
#pragma unroll
            for (int q = 0; q < 12; q++) {  // 24 random LDS gathers
                vv[2 * q]     = *(const float*)(vb + (wq[q] & 0xffffu));
                vv[2 * q + 1] = *(const float*)(vb + (wq[q] >> 16));
            }
            float body[S];
#pragma unroll
            for (int ss = 0; ss < S; ss++)
                body[ss] = vv[ss * 3] * vv[ss * 3 + 1] * vv[ss * 3 + 2];
            float bm = body[0];
#pragma unroll
            for (int ss = 1; ss < S; ss++) bm = fmaxf(bm, body[ss]);
            float sum = 0.f;
#pragma unroll
            for (int ss = 0; ss < S; ss++)
                sum += exp2f((body[ss] - bm) * K_EXP);
            float y = fmaf(K_LOG, log2f(sum), bm);   // unscaled Cv value
            ymax = fmaxf(ymax, y);
            // fused einsum: h[m] += Ws[m,c] * y   (s1 applied later, linear)
#pragma unroll
            for (int m = 0; m < M; m++)
                h[m] = fmaf(Wst[c * M + m], y, h[m]);
            if (c + 1 < C) { w0 = n0; w1 = n1; w2 = n2; }
        }
        {
            float4* Hp = (float4*)(H + ((size_t)i << 4));
            Hp[0] = make_float4(h[0],  h[1],  h[2],  h[3]);
            Hp[1] = make_float4(h[4],  h[5],  h[6],  h[7]);
            Hp[2] = make_float4(h[8],  h[9],  h[10], h[11]);
            Hp[3] = make_float4(h[12], h[13], h[14], h[15]);
        }
        blockMaxOut(ymax, scratch, Pm1);
        grid.sync();

        // ---------------- phase B ----------------
        {
            float m1 = blockMaxBcast(Pm1[t], scratch);
            float s1 = (m1 > 1.0f) ? 1.0f / m1 : 1.0f;
            const float4* hp = (const float4*)(H + ((size_t)i << 4));
            float4 a0 = hp[0], a1 = hp[1], a2 = hp[2], a3 = hp[3];
            float hv[M] = {a0.x, a0.y, a0.z, a0.w, a1.x, a1.y, a1.z, a1.w,
                           a2.x, a2.y, a2.z, a2.w, a3.x, a3.y, a3.z, a3.w};
            float hm = -INFINITY;
#pragma unroll
            for (int m = 0; m < M; m++) {
                hv[m] *= s1;
                hm = fmaxf(hm, hv[m]);
            }
            float sum = 0.f;
#pragma unroll
            for (int m = 0; m < M; m++) sum += exp2f((hv[m] - hm) * K_EXP);
            float y = fmaf(K_LOG, log2f(sum), hm);
            Hy[i] = y;
            blockMaxOut(y, scratch, Pm2);
        }
        grid.sync();

        // ---------------- phase C ----------------
        {
            float m2 = blockMaxBcast(Pm2[t], scratch);
            float s2 = (m2 > 1.0f) ? 1.0f / m2 : 1.0f;
            float Rv = Vrow[g];               // = sp * Rprev (still in LDS)
            float rv = s2 * Hy[i];
            float a = fmaxf(Rv, rv), d = fminf(Rv, rv);
            float y = fmaf(K_LOG, log2f(1.0f + exp2f((d - a) * K_EXP)), a);
            Ry[i] = y;
            blockMaxOut(y, scratch, Pm3);
        }
        Vsrc = Ry;
        grid.sync();
    }

    // ---------------- output ----------------
    float m3 = blockMaxBcast(Pm3[t], scratch);
    float sf = (m3 > 1.0f) ? 1.0f / m3 : 1.0f;
    out[i] = sf * Ry[i];
}

extern "C" void kernel_launch(void* const* d_in, const int* in_sizes, int n_in,
                              void* d_out, int out_size, void* d_ws, size_t ws_size,
                              hipStream_t stream) {
    const float* x = (const float*)d_in[0];   // (B,G)
    const float* W = (const float*)d_in[1];   // (M,C)
    const int*   I = (const int*)d_in[2];     // (C,G,S,L)
    float* out = (float*)d_out;

    float* ws  = (float*)d_ws;
    float* Wst = ws;                               // 256
    float* Pm1 = Wst + 256;                        // 256
    float* Pm2 = Pm1 + 256;                        // 256
    float* Pm3 = Pm2 + 256;                        // 256
    float* H   = Pm3 + 256;                        // B*G*M = 1,048,576 floats
    float* Hy  = H + (size_t)B * G * M;            // B*G
    float* Ry  = Hy + (size_t)B * G;               // B*G
    unsigned int* Ipk = (unsigned int*)(Ry + (size_t)B * G);  // C*G*S*L/2 uints

    void* args[] = {(void*)&x,   (void*)&W,   (void*)&I,   (void*)&Ipk,
                    (void*)&Wst, (void*)&Pm1, (void*)&Pm2, (void*)&Pm3,
                    (void*)&H,   (void*)&Hy,  (void*)&Ry,  (void*)&out};
    hipLaunchCooperativeKernel((const void*)kmain, dim3(B * G / 256), dim3(256),
                               args, 0, stream);
}

// Round 2
// 145.526 us; speedup vs baseline: 4.1679x; 4.1679x over previous
//
#include <hip/hip_runtime.h>

#define GAMMA 0.01f
#define B 32
#define G 2048
#define C 16
#define S 8
#define L 3
#define M 16
#define Q 24                          // S*L offsets per (c,g)

// lse in base-2: exp(v/g) = exp2(v * K_EXP); g*log(s) = K_LOG * log2(s)
#define K_EXP 144.26950408889634f     // log2(e) / GAMMA
#define K_LOG 0.006931471805599453f   // GAMMA * ln(2)

__device__ __forceinline__ float waveMax(float v) {
#pragma unroll
    for (int off = 32; off > 0; off >>= 1)
        v = fmaxf(v, __shfl_xor(v, off, 64));
    return v;
}

// 256-thread (4-wave) block max, broadcast. Leading sync guards scratch reuse.
__device__ __forceinline__ float blockMaxBcast(float v, float* scratch) {
    float wm = waveMax(v);
    __syncthreads();
    if ((threadIdx.x & 63) == 0) scratch[threadIdx.x >> 6] = wm;
    __syncthreads();
    return fmaxf(fmaxf(scratch[0], scratch[1]), fmaxf(scratch[2], scratch[3]));
}

// 512-thread (8-wave) block max, broadcast.
__device__ __forceinline__ float blockMaxBcast8(float v, float* scratch) {
    float wm = waveMax(v);
    __syncthreads();
    if ((threadIdx.x & 63) == 0) scratch[threadIdx.x >> 6] = wm;
    __syncthreads();
    float r = scratch[0];
#pragma unroll
    for (int j = 1; j < 8; j++) r = fmaxf(r, scratch[j]);
    return r;
}

// One-time: pack I -> u16 byte-offsets (idx*16, transposed [c][q][g]) and
// Ws = softmax(W, axis=1).
__global__ __launch_bounds__(256) void kinit(
    const float* __restrict__ W, const int* __restrict__ I,
    float* __restrict__ Ws, unsigned short* __restrict__ Ipk) {
    const int t = blockIdx.x * 256 + threadIdx.x;   // over C*G = 32768
    const int c = t >> 11, g = t & 2047;
    const int4* ip4 = (const int4*)(I + ((size_t)c * G + g) * Q);
    int idx[Q];
#pragma unroll
    for (int j = 0; j < 6; j++) {
        int4 v = ip4[j];
        idx[4 * j + 0] = v.x; idx[4 * j + 1] = v.y;
        idx[4 * j + 2] = v.z; idx[4 * j + 3] = v.w;
    }
#pragma unroll
    for (int q = 0; q < Q; q++)
        Ipk[((size_t)c * Q + q) * G + g] = (unsigned short)(idx[q] << 4);

    if (blockIdx.x == 0) {            // Ws[m*C+c] = softmax(W, axis=1)
        const int m = threadIdx.x >> 4, cc = threadIdx.x & 15;
        float rmax = -INFINITY;
#pragma unroll
        for (int j = 0; j < C; j++) rmax = fmaxf(rmax, W[m * C + j]);
        float rsum = 0.f;
#pragma unroll
        for (int j = 0; j < C; j++) rsum += __expf(W[m * C + j] - rmax);
        Ws[m * C + cc] = __expf(W[m * C + cc] - rmax) / rsum;
    }
}

// K1: 256 blocks x 512 threads. Block = (bq = z: 4 b-rows, cg = y: 8 c's,
// gt = x: 128 g's). Stages 4 V-rows interleaved V4[g][4] (32 KB), gathers with
// one ds_read_b128 per index serving all 4 rows.
// Thread: g = t&127, cq = t>>7 -> c = cg*8 + cq*2 + {0,1}.
// Per-block max -> Pm1[(bq*2+cg)*16+gt] (256 partials).
__global__ __launch_bounds__(512) void k1(
    const float* __restrict__ Vsrc, const float* __restrict__ Pm3prev,
    const unsigned short* __restrict__ Ipk,
    float* __restrict__ Cv, float* __restrict__ Pm1) {
    __shared__ __align__(16) float V4[G * 4];   // 32 KB: [g][4] b-interleaved
    __shared__ float scratch[8];
    const int t = threadIdx.x;
    const int gt = blockIdx.x, cg = blockIdx.y, bq = blockIdx.z;
    const int b0 = bq * 4;

    float s = 1.0f;
    if (Pm3prev) {                   // uniform branch
        float m3 = blockMaxBcast8(Pm3prev[t & 255], scratch);
        s = (m3 > 1.0f) ? 1.0f / m3 : 1.0f;
    }

    // Stage: lane (bb = t&3, gb = t>>2) -> conflict-free LDS writes
    // (bank = t mod 32, 2-way = free); global reads 4x64B segments per wave.
    {
        const int bb = t & 3, gb = t >> 2;
        const float* src = Vsrc + (size_t)(b0 + bb) * G;
#pragma unroll
        for (int k = 0; k < 16; k++) {
            const int g = gb + (k << 7);
            V4[(g << 2) + bb] = s * src[g];
        }
    }
    __syncthreads();

    const int g = (gt << 7) + (t & 127);
    const int cbase = cg * 8 + (t >> 7) * 2;
    const char* vb = (const char*)V4;
    float ymax = -INFINITY;

#pragma unroll
    for (int cc = 0; cc < 2; cc++) {
        const int c = cbase + cc;
        const unsigned short* ip = Ipk + (size_t)c * Q * G + g;
        unsigned int off[Q];
#pragma unroll
        for (int q = 0; q < Q; q++) off[q] = ip[(size_t)q * G];   // coalesced u16

        float4 body[S];
#pragma unroll
        for (int ss = 0; ss < S; ss++) {
            float4 v0 = *(const float4*)(vb + off[ss * 3 + 0]);
            float4 v1 = *(const float4*)(vb + off[ss * 3 + 1]);
            float4 v2 = *(const float4*)(vb + off[ss * 3 + 2]);
            body[ss] = make_float4(v0.x * v1.x * v2.x, v0.y * v1.y * v2.y,
                                   v0.z * v1.z * v2.z, v0.w * v1.w * v2.w);
        }
        float4 bm = body[0];
#pragma unroll
        for (int ss = 1; ss < S; ss++) {
            bm.x = fmaxf(bm.x, body[ss].x); bm.y = fmaxf(bm.y, body[ss].y);
            bm.z = fmaxf(bm.z, body[ss].z); bm.w = fmaxf(bm.w, body[ss].w);
        }
        float4 sum = make_float4(0.f, 0.f, 0.f, 0.f);
#pragma unroll
        for (int ss = 0; ss < S; ss++) {
            sum.x += exp2f((body[ss].x - bm.x) * K_EXP);
            sum.y += exp2f((body[ss].y - bm.y) * K_EXP);
            sum.z += exp2f((body[ss].z - bm.z) * K_EXP);
            sum.w += exp2f((body[ss].w - bm.w) * K_EXP);
        }
        float4 y;
        y.x = fmaf(K_LOG, log2f(sum.x), bm.x);
        y.y = fmaf(K_LOG, log2f(sum.y), bm.y);
        y.z = fmaf(K_LOG, log2f(sum.z), bm.z);
        y.w = fmaf(K_LOG, log2f(sum.w), bm.w);

        const size_t cgo = (size_t)c * G + g;
        Cv[(size_t)(b0 + 0) * (C * G) + cgo] = y.x;
        Cv[(size_t)(b0 + 1) * (C * G) + cgo] = y.y;
        Cv[(size_t)(b0 + 2) * (C * G) + cgo] = y.z;
        Cv[(size_t)(b0 + 3) * (C * G) + cgo] = y.w;
        ymax = fmaxf(ymax, fmaxf(fmaxf(y.x, y.y), fmaxf(y.z, y.w)));
    }

    // per-block max -> Pm1[bid]
    float wm = waveMax(ymax);
    __syncthreads();
    if ((t & 63) == 0) scratch[t >> 6] = wm;
    __syncthreads();
    if (t == 0) {
        float r = scratch[0];
#pragma unroll
        for (int j = 1; j < 8; j++) r = fmaxf(r, scratch[j]);
        Pm1[(bq * 2 + cg) * 16 + gt] = r;
    }
}

// K2: H[m] = sum_c Ws[m,c]*(s1*Cv[b,c,g]); Hy = gamma*lse_m(H/gamma)
__global__ __launch_bounds__(256) void k2(
    const float* __restrict__ Cv, const float* __restrict__ Ws,
    const float* __restrict__ Pm1, float* __restrict__ Hy, float* __restrict__ Pm2) {
    __shared__ float WsL[M * C];
    __shared__ float scratch[4];
    const int b = blockIdx.y, gt = blockIdx.x, t = threadIdx.x;

    WsL[t] = Ws[t];                          // covered by blockMaxBcast's syncs
    float m1 = blockMaxBcast(Pm1[t], scratch);
    float s1 = (m1 > 1.0f) ? 1.0f / m1 : 1.0f;

    const int g = gt * 256 + t;
    float cv[C];
#pragma unroll
    for (int c = 0; c < C; c++)
        cv[c] = s1 * Cv[((size_t)b * C + c) * G + g];

    float h[M];
    float hm = -INFINITY;
#pragma unroll
    for (int m = 0; m < M; m++) {
        float acc = 0.f;
#pragma unroll
        for (int c = 0; c < C; c++) acc = fmaf(WsL[m * C + c], cv[c], acc);
        h[m] = acc; hm = fmaxf(hm, acc);
    }
    float sum = 0.f;
#pragma unroll
    for (int m = 0; m < M; m++) sum += exp2f((h[m] - hm) * K_EXP);
    float y = fmaf(K_LOG, log2f(sum), hm);
    Hy[(size_t)b * G + g] = y;

    float wm = waveMax(y);
    __syncthreads();
    if ((t & 63) == 0) scratch[t >> 6] = wm;
    __syncthreads();
    if (t == 0)
        Pm2[b * 8 + gt] =
            fmaxf(fmaxf(scratch[0], scratch[1]), fmaxf(scratch[2], scratch[3]));
}

// K3: Ry = gamma*lse_2(sp*Rprev, s2*Hy). Per-block max -> Pm3[blockIdx.x].
__global__ __launch_bounds__(256) void k3(
    const float* __restrict__ Rprev, const float* __restrict__ Pm3prev,
    const float* __restrict__ Hy, const float* __restrict__ Pm2,
    float* __restrict__ Ry, float* __restrict__ Pm3) {
    __shared__ float scratch[4];
    const int t = threadIdx.x;
    const int i = blockIdx.x * 256 + t;

    float sp = 1.0f;
    if (Pm3prev) {                   // uniform branch
        float m = blockMaxBcast(Pm3prev[t], scratch);
        sp = (m > 1.0f) ? 1.0f / m : 1.0f;
    }
    float m2 = blockMaxBcast(Pm2[t], scratch);
    float s2 = (m2 > 1.0f) ? 1.0f / m2 : 1.0f;

    float Rv = sp * Rprev[i];
    float rv = s2 * Hy[i];
    float a = fmaxf(Rv, rv), d = fminf(Rv, rv);
    float y = fmaf(K_LOG, log2f(1.0f + exp2f((d - a) * K_EXP)), a);
    Ry[i] = y;

    float wm = waveMax(y);
    __syncthreads();
    if ((t & 63) == 0) scratch[t >> 6] = wm;
    __syncthreads();
    if (t == 0)
        Pm3[blockIdx.x] =
            fmaxf(fmaxf(scratch[0], scratch[1]), fmaxf(scratch[2], scratch[3]));
}

__global__ __launch_bounds__(256) void kout(
    const float* __restrict__ Ry, const float* __restrict__ Pm3,
    float* __restrict__ out) {
    __shared__ float scratch[4];
    const int t = threadIdx.x;
    const int i = blockIdx.x * 256 + t;
    float m = blockMaxBcast(Pm3[t], scratch);
    float s = (m > 1.0f) ? 1.0f / m : 1.0f;
    out[i] = s * Ry[i];
}

extern "C" void kernel_launch(void* const* d_in, const int* in_sizes, int n_in,
                              void* d_out, int out_size, void* d_ws, size_t ws_size,
                              hipStream_t stream) {
    const float* x = (const float*)d_in[0];   // (B,G)
    const float* W = (const float*)d_in[1];   // (M,C)
    const int*   I = (const int*)d_in[2];     // (C,G,S,L)
    float* out = (float*)d_out;

    float* ws  = (float*)d_ws;
    float* Ws  = ws;                               // 256
    float* Pm1 = Ws + 256;                         // 5 * 256
    float* Pm2 = Pm1 + 5 * 256;                    // 5 * 256
    float* Pm3 = Pm2 + 5 * 256;                    // 5 * 256
    float* Cv  = Pm3 + 5 * 256;                    // B*C*G
    float* Hy  = Cv + (size_t)B * C * G;           // B*G
    float* Ry  = Hy + (size_t)B * G;               // B*G
    unsigned short* Ipk = (unsigned short*)(Ry + (size_t)B * G);  // C*G*Q u16

    kinit<<<dim3(C * G / 256), 256, 0, stream>>>(W, I, Ws, Ipk);

    const float* V = x;
    const float* p3prev = nullptr;
    for (int it = 0; it < 5; it++) {
        float* pm1 = Pm1 + it * 256;
        float* pm2 = Pm2 + it * 256;
        float* pm3 = Pm3 + it * 256;
        k1<<<dim3(16, 2, 8), 512, 0, stream>>>(V, p3prev, Ipk, Cv, pm1);
        k2<<<dim3(8, B), 256, 0, stream>>>(Cv, Ws, pm1, Hy, pm2);
        k3<<<dim3((B * G) / 256), 256, 0, stream>>>(V, p3prev, Hy, pm2, Ry, pm3);
        V = Ry;
        p3prev = pm3;
    }
    kout<<<(B * G) / 256, 256, 0, stream>>>(Ry, Pm3 + 4 * 256, out);
}